// Round 1
// baseline (1173.458 us; speedup 1.0000x reference)
//
#include <hip/hip_runtime.h>

// KVGather: out[n,i,k,:,:] = r_weight[n,i,k] * kv[n, r_idx[n,i,k], :, :]
// N=16, P2=64, W2=64, C_KV=512, TOPK=8
// Row size = W2*C_KV = 32768 floats = 128 KiB. 8192 (n,i,k) triples.

#define ROW_FLOATS   32768      // W2 * C_KV
#define ROW_FLOAT4   8192       // ROW_FLOATS / 4
#define TOPK         8
#define P2           64

__global__ __launch_bounds__(256) void kvgather_kernel(
    const int*   __restrict__ r_idx,     // [N, P2, TOPK]
    const float* __restrict__ r_weight,  // [N, P2, TOPK]
    const float* __restrict__ kv,        // [N, P2, W2, C_KV]
    float*       __restrict__ out)       // [N, P2, TOPK, W2, C_KV]
{
    const int b  = blockIdx.x;           // 0 .. N*P2*TOPK-1, b = (n*P2 + i)*TOPK + k
    const int ni = b >> 3;               // n*P2 + i   (TOPK = 8)
    const int n  = ni >> 6;              // P2 = 64

    const int   idx = r_idx[b];          // region index in [0, P2)
    const float w   = r_weight[b];

    const float4* __restrict__ src =
        (const float4*)(kv + ((size_t)(n * P2 + idx)) * ROW_FLOATS);
    float4* __restrict__ dst = (float4*)(out + (size_t)b * ROW_FLOATS);

    // 8192 float4 per row / 256 threads = 32 iterations, fully coalesced.
    #pragma unroll 4
    for (int t = threadIdx.x; t < ROW_FLOAT4; t += 256) {
        float4 v = src[t];
        v.x *= w; v.y *= w; v.z *= w; v.w *= w;
        dst[t] = v;
    }
}

extern "C" void kernel_launch(void* const* d_in, const int* in_sizes, int n_in,
                              void* d_out, int out_size, void* d_ws, size_t ws_size,
                              hipStream_t stream) {
    const int*   r_idx    = (const int*)d_in[0];
    const float* r_weight = (const float*)d_in[1];
    const float* kv       = (const float*)d_in[2];
    float*       out      = (float*)d_out;

    const int n_triples = in_sizes[0];   // N*P2*TOPK = 8192
    kvgather_kernel<<<n_triples, 256, 0, stream>>>(r_idx, r_weight, kv, out);
}